// Round 11
// baseline (171.827 us; speedup 1.0000x reference)
//
#include <hip/hip_runtime.h>
#include <stdint.h>

// Permutohedral splat, round 11: round-6 pipeline (CHUNK=64, KCAP=2^20)
// restructured around a COMPACT CELL LIST:
//  - k_hist: counting atomicAdd also yields each point's within-cell slot;
//    first toucher appends key to cellList (one cursor atomic per cell, ~4k).
//  - k_cscan: single-block scan over only the occupied cells -> offsets.
//  - k_scatter: atomic-free placement via offsets[key] + slot.
//  - k_reduce: unchanged (exact-h[4] run flush, order-agnostic).
// 6 dispatches total (was 8); no 1M-bin scan traffic; no atomicSub pass.
// N=262144, D=3, V=64, CAPACITY=2^20 table rows, KCAP=2^20 bins.

#define CAPACITY (1u << 20)
#define KCAP     (1u << 20)
#define TBL_W    65
#define CHUNK    64

// ---------------- lattice math (validated rounds 0-10) ----------------
__device__ __forceinline__ void lattice_all(const float* __restrict__ pos, int point,
                                            uint32_t h[4], float w[4], uint32_t* keyOut)
{
    const float scale0 = 2.3094010767585034f;
    const float scale1 = 1.3333333333333333f;
    const float scale2 = 0.9428090415820634f;

    const float cf0 = pos[point * 3 + 0] * scale0;
    const float cf1 = pos[point * 3 + 1] * scale1;
    const float cf2 = pos[point * 3 + 2] * scale2;

    const float t1 = cf2 + cf1;
    float elev[4];
    elev[0] = t1 + cf0;
    elev[1] = t1 - cf0;
    elev[2] = cf2 - 2.0f * cf1;
    elev[3] = -3.0f * cf2;

    float rem0[4];
    float rd_s = 0.0f;
#pragma unroll
    for (int j = 0; j < 4; ++j) {
        float rd = rintf(elev[j] * 0.25f);
        rem0[j] = rd * 4.0f;
        rd_s += rd;
    }
    const int rd_sum = (int)rd_s;

    float diff[4];
#pragma unroll
    for (int j = 0; j < 4; ++j) diff[j] = elev[j] - rem0[j];

    int rank[4];
#pragma unroll
    for (int i = 0; i < 4; ++i) {
        int r = 0;
#pragma unroll
        for (int j = 0; j < 4; ++j) {
            if (diff[j] > diff[i] || (diff[j] == diff[i] && j < i)) r++;
        }
        rank[i] = r + rd_sum;
    }

#pragma unroll
    for (int i = 0; i < 4; ++i) {
        if (rank[i] < 0)      { rank[i] += 4; rem0[i] += 4.0f; }
        else if (rank[i] > 3) { rank[i] -= 4; rem0[i] -= 4.0f; }
    }

    float delta[4];
#pragma unroll
    for (int i = 0; i < 4; ++i) delta[i] = (elev[i] - rem0[i]) * 0.25f;

    float b[5] = {0.f, 0.f, 0.f, 0.f, 0.f};
#pragma unroll
    for (int i = 0; i < 4; ++i) {
        int k1 = 3 - rank[i];
        int k2 = 4 - rank[i];
        if (k1 >= 0 && k1 < 5) b[k1] += delta[i];
        if (k2 >= 0 && k2 < 5) b[k2] -= delta[i];
    }
    w[0] = b[0] + (1.0f + b[4]);
    w[1] = b[1];
    w[2] = b[2];
    w[3] = b[3];

    const uint32_t P0 = 2654435761u, P1 = 805459861u, P2 = 3674653429u;
    const int k0  = (int)rem0[0];
    const int k1i = (int)rem0[1];
    const int k2i = (int)rem0[2];

#pragma unroll
    for (int r = 0; r < 4; ++r) {
        int o0 = (rank[0] < 4 - r) ? r : r - 4;
        int o1 = (rank[1] < 4 - r) ? r : r - 4;
        int o2 = (rank[2] < 4 - r) ? r : r - 4;
        uint32_t hh = (uint32_t)(k0 + o0)  * P0
                    + (uint32_t)(k1i + o1) * P1
                    + (uint32_t)(k2i + o2) * P2;
        h[r] = hh & (CAPACITY - 1u);
    }

    const uint32_t pidx = (uint32_t)(rank[0] * 16 + rank[1] * 4 + rank[2]);
    uint32_t key = (uint32_t)k0 * P0 + (uint32_t)k1i * P1 + (uint32_t)k2i * P2
                 + pidx * 0x9E3779B9u;
    *keyOut = key & (KCAP - 1u);
}

// ---------------- pipeline kernels ----------------
// hist: per-point key + within-cell slot; first toucher appends to cellList.
__global__ __launch_bounds__(256) void k_hist(const float* __restrict__ pos,
                                              uint32_t* __restrict__ counts,
                                              uint32_t* __restrict__ cursor,
                                              uint32_t* __restrict__ cellList,
                                              uint32_t* __restrict__ keys,
                                              uint32_t* __restrict__ slots, int n)
{
    int p = blockIdx.x * blockDim.x + threadIdx.x;
    if (p >= n) return;
    uint32_t h[4]; float w[4]; uint32_t key;
    lattice_all(pos, p, h, w, &key);
    keys[p] = key;
    const uint32_t old = atomicAdd(&counts[key], 1u);
    slots[p] = old;
    if (old == 0u) {
        const uint32_t idx = atomicAdd(cursor, 1u);
        cellList[idx] = key;
    }
}

// Single-block exclusive scan over the occupied cells only.
__global__ __launch_bounds__(1024) void k_cscan(const uint32_t* __restrict__ counts,
                                                const uint32_t* __restrict__ cellList,
                                                const uint32_t* __restrict__ cursor,
                                                uint32_t* __restrict__ offsets)
{
    __shared__ uint32_t s[1024];
    const int t = threadIdx.x;
    const uint32_t ncells = *cursor;
    uint32_t carry = 0;

    for (uint32_t base = 0; base < ncells; base += 1024u) {
        const uint32_t i = base + (uint32_t)t;
        uint32_t key = 0u, c = 0u;
        if (i < ncells) { key = cellList[i]; c = counts[key]; }
        s[t] = c;
        __syncthreads();
        for (int o = 1; o < 1024; o <<= 1) {
            uint32_t x = s[t];
            uint32_t y = (t >= o) ? s[t - o] : 0u;
            __syncthreads();
            s[t] = x + y;
            __syncthreads();
        }
        const uint32_t incl = s[t];
        const uint32_t btot = s[1023];
        if (i < ncells) offsets[key] = carry + incl - c;   // exclusive
        carry += btot;
        __syncthreads();    // protect s[] before next chunk overwrites
    }
}

// Atomic-free scatter using precomputed slot.
__global__ __launch_bounds__(256) void k_scatter(const uint32_t* __restrict__ keys,
                                                 const uint32_t* __restrict__ slots,
                                                 const uint32_t* __restrict__ offsets,
                                                 uint32_t* __restrict__ sorted, int n)
{
    int p = blockIdx.x * blockDim.x + threadIdx.x;
    if (p >= n) return;
    sorted[offsets[keys[p]] + slots[p]] = (uint32_t)p;
}

// One wave per CHUNK(=64) sorted points; run-detection by exact h[4] compare;
// each vals row read exactly once; 4x65 atomic flush per run boundary.
__global__ __launch_bounds__(256) void k_reduce(const uint32_t* __restrict__ sorted,
                                                const float* __restrict__ pos,
                                                const float* __restrict__ vals,
                                                float* __restrict__ table, int N)
{
    const int gtid = blockIdx.x * blockDim.x + threadIdx.x;
    const int wid  = gtid >> 6;
    const int lane = threadIdx.x & 63;
    const int base = wid * CHUNK;
    if (base >= N) return;
    const int cnt = min(CHUNK, N - base);

    const int e = (lane < cnt) ? lane : 0;
    const int mypid = (int)sorted[base + e];

    uint32_t mh[4]; float mw[4]; uint32_t dummyKey;
    lattice_all(pos, mypid, mh, mw, &dummyKey);

    uint32_t h0p = __shfl(mh[0], 0);
    uint32_t h1p = __shfl(mh[1], 0);
    uint32_t h2p = __shfl(mh[2], 0);
    uint32_t h3p = __shfl(mh[3], 0);

    float acc0 = 0.f, acc1 = 0.f, acc2 = 0.f, acc3 = 0.f;
    float aW0 = 0.f, aW1 = 0.f, aW2 = 0.f, aW3 = 0.f;

    for (int eb = 0; eb < cnt; eb += 8) {
        const int m = min(8, cnt - eb);
        float row[8];
#pragma unroll
        for (int j = 0; j < 8; ++j) {
            const int pj = __shfl(mypid, (eb + j) & (CHUNK - 1));
            row[j] = (j < m) ? vals[(size_t)pj * 64 + lane] : 0.f;
        }
#pragma unroll
        for (int j = 0; j < 8; ++j) {
            if (j >= m) break;
            const int src = eb + j;
            const uint32_t h0c = __shfl(mh[0], src);
            const uint32_t h1c = __shfl(mh[1], src);
            const uint32_t h2c = __shfl(mh[2], src);
            const uint32_t h3c = __shfl(mh[3], src);
            if ((h0c != h0p) | (h1c != h1p) | (h2c != h2p) | (h3c != h3p)) {
                atomicAdd(&table[(size_t)h0p * TBL_W + lane], acc0);
                atomicAdd(&table[(size_t)h1p * TBL_W + lane], acc1);
                atomicAdd(&table[(size_t)h2p * TBL_W + lane], acc2);
                atomicAdd(&table[(size_t)h3p * TBL_W + lane], acc3);
                if (lane == 0) {
                    atomicAdd(&table[(size_t)h0p * TBL_W + 64], aW0);
                    atomicAdd(&table[(size_t)h1p * TBL_W + 64], aW1);
                    atomicAdd(&table[(size_t)h2p * TBL_W + 64], aW2);
                    atomicAdd(&table[(size_t)h3p * TBL_W + 64], aW3);
                }
                acc0 = acc1 = acc2 = acc3 = 0.f;
                aW0 = aW1 = aW2 = aW3 = 0.f;
                h0p = h0c; h1p = h1c; h2p = h2c; h3p = h3c;
            }
            const float w0 = __shfl(mw[0], src);
            const float w1 = __shfl(mw[1], src);
            const float w2 = __shfl(mw[2], src);
            const float w3 = __shfl(mw[3], src);
            acc0 += w0 * row[j];
            acc1 += w1 * row[j];
            acc2 += w2 * row[j];
            acc3 += w3 * row[j];
            aW0 += w0; aW1 += w1; aW2 += w2; aW3 += w3;
        }
    }
    atomicAdd(&table[(size_t)h0p * TBL_W + lane], acc0);
    atomicAdd(&table[(size_t)h1p * TBL_W + lane], acc1);
    atomicAdd(&table[(size_t)h2p * TBL_W + lane], acc2);
    atomicAdd(&table[(size_t)h3p * TBL_W + lane], acc3);
    if (lane == 0) {
        atomicAdd(&table[(size_t)h0p * TBL_W + 64], aW0);
        atomicAdd(&table[(size_t)h1p * TBL_W + 64], aW1);
        atomicAdd(&table[(size_t)h2p * TBL_W + 64], aW2);
        atomicAdd(&table[(size_t)h3p * TBL_W + 64], aW3);
    }
}

// ---------------- fallback (ws too small) ----------------
__global__ __launch_bounds__(256) void splat_fallback(const float* __restrict__ pos,
                                                      const float* __restrict__ vals,
                                                      float* __restrict__ table, int n)
{
    const int gtid  = blockIdx.x * blockDim.x + threadIdx.x;
    const int point = gtid >> 6;
    const int lane  = threadIdx.x & 63;
    if (point >= n) return;
    uint32_t h[4]; float w[4]; uint32_t key;
    lattice_all(pos, point, h, w, &key);
    const float v = vals[(size_t)point * 64 + lane];
#pragma unroll
    for (int r = 0; r < 4; ++r)
        atomicAdd(&table[(size_t)h[r] * TBL_W + lane], w[r] * v);
    if (lane == 0) {
#pragma unroll
        for (int r = 0; r < 4; ++r)
            atomicAdd(&table[(size_t)h[r] * TBL_W + 64], w[r]);
    }
}

// ---------------- host launch ----------------
extern "C" void kernel_launch(void* const* d_in, const int* in_sizes, int n_in,
                              void* d_out, int out_size, void* d_ws, size_t ws_size,
                              hipStream_t stream) {
    const float* pos  = (const float*)d_in[0];
    const float* vals = (const float*)d_in[1];
    float* table      = (float*)d_out;

    const int n = in_sizes[0] / 3;        // 262144

    // Zero output table (runtime fill measured at 86-88% of HBM peak).
    hipMemsetAsync(d_out, 0, (size_t)out_size * sizeof(float), stream);

    // Workspace layout: counts | cursor | offsets | cellList | keys | slots | sorted
    const size_t offCnt  = 0;                          // KCAP*4 = 4 MB
    const size_t offCur  = offCnt + (size_t)KCAP * 4;  // 64 B
    const size_t offOff  = offCur + 64;                // KCAP*4 = 4 MB
    const size_t offCell = offOff + (size_t)KCAP * 4;  // n*4
    const size_t offKeys = offCell + (size_t)n * 4;    // n*4
    const size_t offSlot = offKeys + (size_t)n * 4;    // n*4
    const size_t offSort = offSlot + (size_t)n * 4;    // n*4
    const size_t REQUIRED = offSort + (size_t)n * 4;

    if (ws_size < REQUIRED) {
        const int blocks = (n * 64 + 255) / 256;
        splat_fallback<<<blocks, 256, 0, stream>>>(pos, vals, table, n);
        return;
    }

    uint8_t* ws = (uint8_t*)d_ws;
    uint32_t* counts   = (uint32_t*)(ws + offCnt);
    uint32_t* cursor   = (uint32_t*)(ws + offCur);
    uint32_t* offsets  = (uint32_t*)(ws + offOff);
    uint32_t* cellList = (uint32_t*)(ws + offCell);
    uint32_t* keys     = (uint32_t*)(ws + offKeys);
    uint32_t* slots    = (uint32_t*)(ws + offSlot);
    uint32_t* sorted   = (uint32_t*)(ws + offSort);

    // Zero counts + cursor in one memset (contiguous).
    hipMemsetAsync(counts, 0, (size_t)KCAP * 4 + 64, stream);

    const int ptBlocks = (n + 255) / 256;               // 1024
    k_hist<<<ptBlocks, 256, 0, stream>>>(pos, counts, cursor, cellList, keys, slots, n);

    k_cscan<<<1, 1024, 0, stream>>>(counts, cellList, cursor, offsets);

    k_scatter<<<ptBlocks, 256, 0, stream>>>(keys, slots, offsets, sorted, n);

    const int nWaves  = (n + CHUNK - 1) / CHUNK;        // 4096
    const int rBlocks = (nWaves + 3) / 4;               // 1024 (4 waves/block)
    k_reduce<<<rBlocks, 256, 0, stream>>>(sorted, pos, vals, table, n);
}

// Round 12
// 113.491 us; speedup vs baseline: 1.5140x; 1.5140x over previous
//
#include <hip/hip_runtime.h>
#include <stdint.h>

// Permutohedral splat, round 12: round-6 pipeline (best: 128.7us) with two
// safe cuts: (1) scanpartials fused into k_offsets (each block reduces its own
// base from the 4KB partials array); (2) atomic-free scatter via slots recorded
// by hist's counting atomicAdd. 7 dispatches. CHUNK=64, KCAP=2^20.
// N=262144, D=3, V=64, CAPACITY=2^20 table rows.

#define CAPACITY (1u << 20)
#define KCAP     (1u << 20)
#define TBL_W    65
#define CHUNK    64

// ---------------- lattice math (validated rounds 0-11) ----------------
__device__ __forceinline__ void lattice_all(const float* __restrict__ pos, int point,
                                            uint32_t h[4], float w[4], uint32_t* keyOut)
{
    const float scale0 = 2.3094010767585034f;
    const float scale1 = 1.3333333333333333f;
    const float scale2 = 0.9428090415820634f;

    const float cf0 = pos[point * 3 + 0] * scale0;
    const float cf1 = pos[point * 3 + 1] * scale1;
    const float cf2 = pos[point * 3 + 2] * scale2;

    const float t1 = cf2 + cf1;
    float elev[4];
    elev[0] = t1 + cf0;
    elev[1] = t1 - cf0;
    elev[2] = cf2 - 2.0f * cf1;
    elev[3] = -3.0f * cf2;

    float rem0[4];
    float rd_s = 0.0f;
#pragma unroll
    for (int j = 0; j < 4; ++j) {
        float rd = rintf(elev[j] * 0.25f);
        rem0[j] = rd * 4.0f;
        rd_s += rd;
    }
    const int rd_sum = (int)rd_s;

    float diff[4];
#pragma unroll
    for (int j = 0; j < 4; ++j) diff[j] = elev[j] - rem0[j];

    int rank[4];
#pragma unroll
    for (int i = 0; i < 4; ++i) {
        int r = 0;
#pragma unroll
        for (int j = 0; j < 4; ++j) {
            if (diff[j] > diff[i] || (diff[j] == diff[i] && j < i)) r++;
        }
        rank[i] = r + rd_sum;
    }

#pragma unroll
    for (int i = 0; i < 4; ++i) {
        if (rank[i] < 0)      { rank[i] += 4; rem0[i] += 4.0f; }
        else if (rank[i] > 3) { rank[i] -= 4; rem0[i] -= 4.0f; }
    }

    float delta[4];
#pragma unroll
    for (int i = 0; i < 4; ++i) delta[i] = (elev[i] - rem0[i]) * 0.25f;

    float b[5] = {0.f, 0.f, 0.f, 0.f, 0.f};
#pragma unroll
    for (int i = 0; i < 4; ++i) {
        int k1 = 3 - rank[i];
        int k2 = 4 - rank[i];
        if (k1 >= 0 && k1 < 5) b[k1] += delta[i];
        if (k2 >= 0 && k2 < 5) b[k2] -= delta[i];
    }
    w[0] = b[0] + (1.0f + b[4]);
    w[1] = b[1];
    w[2] = b[2];
    w[3] = b[3];

    const uint32_t P0 = 2654435761u, P1 = 805459861u, P2 = 3674653429u;
    const int k0  = (int)rem0[0];
    const int k1i = (int)rem0[1];
    const int k2i = (int)rem0[2];

#pragma unroll
    for (int r = 0; r < 4; ++r) {
        int o0 = (rank[0] < 4 - r) ? r : r - 4;
        int o1 = (rank[1] < 4 - r) ? r : r - 4;
        int o2 = (rank[2] < 4 - r) ? r : r - 4;
        uint32_t hh = (uint32_t)(k0 + o0)  * P0
                    + (uint32_t)(k1i + o1) * P1
                    + (uint32_t)(k2i + o2) * P2;
        h[r] = hh & (CAPACITY - 1u);
    }

    const uint32_t pidx = (uint32_t)(rank[0] * 16 + rank[1] * 4 + rank[2]);
    uint32_t key = (uint32_t)k0 * P0 + (uint32_t)k1i * P1 + (uint32_t)k2i * P2
                 + pidx * 0x9E3779B9u;
    *keyOut = key & (KCAP - 1u);
}

// ---------------- pipeline kernels ----------------
// hist: counting atomicAdd also records each point's within-cell slot.
__global__ __launch_bounds__(256) void k_hist(const float* __restrict__ pos,
                                              uint32_t* __restrict__ counts,
                                              uint32_t* __restrict__ keys,
                                              uint32_t* __restrict__ slots, int n)
{
    int p = blockIdx.x * blockDim.x + threadIdx.x;
    if (p >= n) return;
    uint32_t h[4]; float w[4]; uint32_t key;
    lattice_all(pos, p, h, w, &key);
    keys[p] = key;
    slots[p] = atomicAdd(&counts[key], 1u);
}

__global__ __launch_bounds__(256) void k_blocksum(const uint32_t* __restrict__ counts,
                                                  uint32_t* __restrict__ partials)
{
    __shared__ uint32_t s[256];
    const int b = blockIdx.x, t = threadIdx.x;
    uint4 v = ((const uint4*)(counts + (size_t)b * 1024))[t];
    s[t] = v.x + v.y + v.z + v.w;
    __syncthreads();
    for (int o = 128; o > 0; o >>= 1) {
        if (t < o) s[t] += s[t + o];
        __syncthreads();
    }
    if (t == 0) partials[b] = s[0];
}

// offsets with fused base computation: block b reduces partials[0..b) itself
// (1024-entry array, L2-broadcast), then per-block scan of its 1024 bins.
__global__ __launch_bounds__(256) void k_offsets(const uint32_t* __restrict__ counts,
                                                 const uint32_t* __restrict__ partials,
                                                 uint32_t* __restrict__ offsets,
                                                 int nblocks)
{
    __shared__ uint32_t s[256];
    const int b = blockIdx.x, t = threadIdx.x;

    // base = sum(partials[0..b))
    uint32_t mysum = 0;
    for (int k = t; k < nblocks; k += 256)
        if (k < b) mysum += partials[k];
    s[t] = mysum;
    __syncthreads();
    for (int o = 128; o > 0; o >>= 1) {
        if (t < o) s[t] += s[t + o];
        __syncthreads();
    }
    const uint32_t base = s[0];
    __syncthreads();

    uint4 v = ((const uint4*)(counts + (size_t)b * 1024))[t];
    const uint32_t s4 = v.x + v.y + v.z + v.w;
    s[t] = s4;
    __syncthreads();
    for (int o = 1; o < 256; o <<= 1) {
        uint32_t x = s[t];
        uint32_t y = (t >= o) ? s[t - o] : 0u;
        __syncthreads();
        s[t] = x + y;
        __syncthreads();
    }
    uint32_t texcl = (s[t] - s4) + base;
    uint4 o4;
    o4.x = texcl;
    o4.y = texcl + v.x;
    o4.z = o4.y + v.y;
    o4.w = o4.z + v.z;
    ((uint4*)(offsets + (size_t)b * 1024))[t] = o4;
}

// Atomic-free scatter using precomputed slots.
__global__ __launch_bounds__(256) void k_scatter(const uint32_t* __restrict__ keys,
                                                 const uint32_t* __restrict__ slots,
                                                 const uint32_t* __restrict__ offsets,
                                                 uint32_t* __restrict__ sorted, int n)
{
    int p = blockIdx.x * blockDim.x + threadIdx.x;
    if (p >= n) return;
    sorted[offsets[keys[p]] + slots[p]] = (uint32_t)p;
}

// One wave per CHUNK(=64) sorted points; run-detection by exact h[4] compare;
// each vals row read exactly once; 4x65 atomic flush per run boundary.
__global__ __launch_bounds__(256) void k_reduce(const uint32_t* __restrict__ sorted,
                                                const float* __restrict__ pos,
                                                const float* __restrict__ vals,
                                                float* __restrict__ table, int N)
{
    const int gtid = blockIdx.x * blockDim.x + threadIdx.x;
    const int wid  = gtid >> 6;
    const int lane = threadIdx.x & 63;
    const int base = wid * CHUNK;
    if (base >= N) return;
    const int cnt = min(CHUNK, N - base);

    const int e = (lane < cnt) ? lane : 0;
    const int mypid = (int)sorted[base + e];

    uint32_t mh[4]; float mw[4]; uint32_t dummyKey;
    lattice_all(pos, mypid, mh, mw, &dummyKey);

    uint32_t h0p = __shfl(mh[0], 0);
    uint32_t h1p = __shfl(mh[1], 0);
    uint32_t h2p = __shfl(mh[2], 0);
    uint32_t h3p = __shfl(mh[3], 0);

    float acc0 = 0.f, acc1 = 0.f, acc2 = 0.f, acc3 = 0.f;
    float aW0 = 0.f, aW1 = 0.f, aW2 = 0.f, aW3 = 0.f;

    for (int eb = 0; eb < cnt; eb += 8) {
        const int m = min(8, cnt - eb);
        float row[8];
#pragma unroll
        for (int j = 0; j < 8; ++j) {
            const int pj = __shfl(mypid, (eb + j) & (CHUNK - 1));
            row[j] = (j < m) ? vals[(size_t)pj * 64 + lane] : 0.f;
        }
#pragma unroll
        for (int j = 0; j < 8; ++j) {
            if (j >= m) break;
            const int src = eb + j;
            const uint32_t h0c = __shfl(mh[0], src);
            const uint32_t h1c = __shfl(mh[1], src);
            const uint32_t h2c = __shfl(mh[2], src);
            const uint32_t h3c = __shfl(mh[3], src);
            if ((h0c != h0p) | (h1c != h1p) | (h2c != h2p) | (h3c != h3p)) {
                atomicAdd(&table[(size_t)h0p * TBL_W + lane], acc0);
                atomicAdd(&table[(size_t)h1p * TBL_W + lane], acc1);
                atomicAdd(&table[(size_t)h2p * TBL_W + lane], acc2);
                atomicAdd(&table[(size_t)h3p * TBL_W + lane], acc3);
                if (lane == 0) {
                    atomicAdd(&table[(size_t)h0p * TBL_W + 64], aW0);
                    atomicAdd(&table[(size_t)h1p * TBL_W + 64], aW1);
                    atomicAdd(&table[(size_t)h2p * TBL_W + 64], aW2);
                    atomicAdd(&table[(size_t)h3p * TBL_W + 64], aW3);
                }
                acc0 = acc1 = acc2 = acc3 = 0.f;
                aW0 = aW1 = aW2 = aW3 = 0.f;
                h0p = h0c; h1p = h1c; h2p = h2c; h3p = h3c;
            }
            const float w0 = __shfl(mw[0], src);
            const float w1 = __shfl(mw[1], src);
            const float w2 = __shfl(mw[2], src);
            const float w3 = __shfl(mw[3], src);
            acc0 += w0 * row[j];
            acc1 += w1 * row[j];
            acc2 += w2 * row[j];
            acc3 += w3 * row[j];
            aW0 += w0; aW1 += w1; aW2 += w2; aW3 += w3;
        }
    }
    atomicAdd(&table[(size_t)h0p * TBL_W + lane], acc0);
    atomicAdd(&table[(size_t)h1p * TBL_W + lane], acc1);
    atomicAdd(&table[(size_t)h2p * TBL_W + lane], acc2);
    atomicAdd(&table[(size_t)h3p * TBL_W + lane], acc3);
    if (lane == 0) {
        atomicAdd(&table[(size_t)h0p * TBL_W + 64], aW0);
        atomicAdd(&table[(size_t)h1p * TBL_W + 64], aW1);
        atomicAdd(&table[(size_t)h2p * TBL_W + 64], aW2);
        atomicAdd(&table[(size_t)h3p * TBL_W + 64], aW3);
    }
}

// ---------------- fallback (ws too small) ----------------
__global__ __launch_bounds__(256) void splat_fallback(const float* __restrict__ pos,
                                                      const float* __restrict__ vals,
                                                      float* __restrict__ table, int n)
{
    const int gtid  = blockIdx.x * blockDim.x + threadIdx.x;
    const int point = gtid >> 6;
    const int lane  = threadIdx.x & 63;
    if (point >= n) return;
    uint32_t h[4]; float w[4]; uint32_t key;
    lattice_all(pos, point, h, w, &key);
    const float v = vals[(size_t)point * 64 + lane];
#pragma unroll
    for (int r = 0; r < 4; ++r)
        atomicAdd(&table[(size_t)h[r] * TBL_W + lane], w[r] * v);
    if (lane == 0) {
#pragma unroll
        for (int r = 0; r < 4; ++r)
            atomicAdd(&table[(size_t)h[r] * TBL_W + 64], w[r]);
    }
}

// ---------------- host launch ----------------
extern "C" void kernel_launch(void* const* d_in, const int* in_sizes, int n_in,
                              void* d_out, int out_size, void* d_ws, size_t ws_size,
                              hipStream_t stream) {
    const float* pos  = (const float*)d_in[0];
    const float* vals = (const float*)d_in[1];
    float* table      = (float*)d_out;

    const int n = in_sizes[0] / 3;        // 262144

    // Zero output table (runtime fill measured at 86-88% of HBM peak).
    hipMemsetAsync(d_out, 0, (size_t)out_size * sizeof(float), stream);

    // Workspace: counts | offsets | partials | keys | slots | sorted
    const size_t offCnt  = 0;                           // KCAP*4 = 4 MB
    const size_t offOff  = offCnt + (size_t)KCAP * 4;   // 4 MB
    const size_t offPart = offOff + (size_t)KCAP * 4;   // 8 KB pad
    const size_t offKeys = offPart + 8192;
    const size_t offSlot = offKeys + (size_t)n * 4;
    const size_t offSort = offSlot + (size_t)n * 4;
    const size_t REQUIRED = offSort + (size_t)n * 4;

    if (ws_size < REQUIRED) {
        const int blocks = (n * 64 + 255) / 256;
        splat_fallback<<<blocks, 256, 0, stream>>>(pos, vals, table, n);
        return;
    }

    uint8_t* ws = (uint8_t*)d_ws;
    uint32_t* counts   = (uint32_t*)(ws + offCnt);
    uint32_t* offsets  = (uint32_t*)(ws + offOff);
    uint32_t* partials = (uint32_t*)(ws + offPart);
    uint32_t* keys     = (uint32_t*)(ws + offKeys);
    uint32_t* slots    = (uint32_t*)(ws + offSlot);
    uint32_t* sorted   = (uint32_t*)(ws + offSort);

    hipMemsetAsync(counts, 0, (size_t)KCAP * 4, stream);

    const int ptBlocks = (n + 255) / 256;               // 1024
    k_hist<<<ptBlocks, 256, 0, stream>>>(pos, counts, keys, slots, n);

    const int scanBlocks = KCAP / 1024;                 // 1024
    k_blocksum<<<scanBlocks, 256, 0, stream>>>(counts, partials);
    k_offsets <<<scanBlocks, 256, 0, stream>>>(counts, partials, offsets, scanBlocks);

    k_scatter<<<ptBlocks, 256, 0, stream>>>(keys, slots, offsets, sorted, n);

    const int nWaves  = (n + CHUNK - 1) / CHUNK;        // 4096
    const int rBlocks = (nWaves + 3) / 4;               // 1024 (4 waves/block)
    k_reduce<<<rBlocks, 256, 0, stream>>>(sorted, pos, vals, table, n);
}